// Round 1
// baseline (248.805 us; speedup 1.0000x reference)
//
#include <hip/hip_runtime.h>
#include <hip/hip_bf16.h>

#define NTOK 8192   // B*S
#define DDIM 1024
#define NEXP 32
#define HDIM 128
#define TOPK 4

typedef __attribute__((ext_vector_type(8))) short bf16x8;
typedef __attribute__((ext_vector_type(4))) float f32x4;

typedef unsigned int uint_g __attribute__((address_space(1)));
typedef unsigned int uint_l __attribute__((address_space(3)));

// async 16B/lane global->LDS; LDS dest = wave-uniform base + lane*16.
// Global source may be per-lane (gather is legal; only the LDS side is constrained).
__device__ __forceinline__ void async_cp16(const void* g, void* l) {
    __builtin_amdgcn_global_load_lds((const uint_g*)g, (uint_l*)l, 16, 0, 0);
}

__device__ inline unsigned short f2bf(float f) {
    unsigned int u = __builtin_bit_cast(unsigned int, f);
    unsigned int r = (u + 0x7fffu + ((u >> 16) & 1u)) >> 16;   // RNE
    return (unsigned short)r;
}
__device__ inline float bf2f(unsigned short s) {
    unsigned int u = ((unsigned int)s) << 16;
    return __builtin_bit_cast(float, u);
}

// ---------------- Kernel P: K/V -> bf16 MFMA-B layout (x handled in gate_partial) ----------------
__global__ __launch_bounds__(256) void prep_weights(
    const float* __restrict__ keys, const float* __restrict__ values,
    unsigned short* __restrict__ Kb, unsigned short* __restrict__ Vb)
{
    int idx = blockIdx.x * 256 + threadIdx.x;
    unsigned short o[8];
    if (idx < NEXP * 128 * 128) {            // keys: (e, k0 [128], n [128])
        int n = idx & 127, k0 = (idx >> 7) & 127, e = idx >> 14;
        const float* s = keys + ((size_t)e * DDIM + k0 * 8) * HDIM + n;
        #pragma unroll
        for (int j = 0; j < 8; ++j) o[j] = f2bf(s[(size_t)j * HDIM]);
        *(uint4*)&Kb[(size_t)idx * 8] = *(uint4*)o;
    } else {                                 // values: (e, k0 [16], n [1024])
        idx -= NEXP * 128 * 128;
        int n = idx & 1023, k0 = (idx >> 10) & 15, e = idx >> 14;
        const float* s = values + ((size_t)e * HDIM + k0 * 8) * DDIM + n;
        #pragma unroll
        for (int j = 0; j < 8; ++j) o[j] = f2bf(s[(size_t)j * DDIM]);
        *(uint4*)&Vb[(size_t)idx * 8] = *(uint4*)o;
    }
}

// ---------------- Kernel G1: gating partial logits (fp32) + fused x->bf16 emit ----------------
__global__ __launch_bounds__(256) void gate_partial(
    const float* __restrict__ x, const float* __restrict__ es,
    float* __restrict__ gpart,               // [4][NTOK][32]
    unsigned short* __restrict__ Xb)         // [NTOK][1024] bf16
{
    const int n0    = blockIdx.x * 16;
    const int dbase = blockIdx.y * 256;
    const int tid   = threadIdx.x;

    __shared__ float smem[4608];             // staging tiles, reused as Lp
    float* Xt  = smem;                       // [d][tok] stride 36
    float* Est = smem + 64 * 36;             // [d][e]   stride 36

    const int t4  = (tid & 3) * 4;
    const int e4  = ((tid >> 2) & 7) * 4;
    const int rep = tid >> 5;

    const int xr = tid & 15, xc4 = (tid >> 4) * 4;
    const int er = tid & 31, ec8 = (tid >> 5) * 8;

    const int ctok = tid >> 4, cd4 = (tid & 15) * 4;   // x->bf16 emit mapping

    float acc[4][4] = {};

    for (int dc = dbase; dc < dbase + 256; dc += 64) {
        __syncthreads();
        {
            float4 v = *(const float4*)&x[(size_t)(n0 + xr) * DDIM + dc + xc4];
            Xt[(xc4 + 0) * 36 + xr] = v.x; Xt[(xc4 + 1) * 36 + xr] = v.y;
            Xt[(xc4 + 2) * 36 + xr] = v.z; Xt[(xc4 + 3) * 36 + xr] = v.w;
        }
        #pragma unroll
        for (int i = 0; i < 2; ++i) {
            float4 v = *(const float4*)&es[(size_t)er * DDIM + dc + ec8 + i * 4];
            Est[(ec8 + i * 4 + 0) * 36 + er] = v.x;
            Est[(ec8 + i * 4 + 1) * 36 + er] = v.y;
            Est[(ec8 + i * 4 + 2) * 36 + er] = v.z;
            Est[(ec8 + i * 4 + 3) * 36 + er] = v.w;
        }
        __syncthreads();

        // fused: emit this x tile as bf16 (each thread 4 contiguous elems of one row)
        {
            unsigned short o[4];
            #pragma unroll
            for (int j = 0; j < 4; ++j) o[j] = f2bf(Xt[(cd4 + j) * 36 + ctok]);
            *(uint2*)&Xb[(size_t)(n0 + ctok) * DDIM + dc + cd4] = *(uint2*)o;
        }

        #pragma unroll
        for (int s = 0; s < 8; ++s) {
            int d = s * 8 + rep;
            float4 xv = *(const float4*)&Xt[d * 36 + t4];
            float4 ev = *(const float4*)&Est[d * 36 + e4];
            const float xa[4] = {xv.x, xv.y, xv.z, xv.w};
            const float ea[4] = {ev.x, ev.y, ev.z, ev.w};
            #pragma unroll
            for (int i = 0; i < 4; ++i)
                #pragma unroll
                for (int j = 0; j < 4; ++j)
                    acc[i][j] = fmaf(xa[i], ea[j], acc[i][j]);
        }
    }

    __syncthreads();
    float* Lp = smem;                         // [rep 8][tok 16][e 33]
    #pragma unroll
    for (int i = 0; i < 4; ++i)
        #pragma unroll
        for (int j = 0; j < 4; ++j)
            Lp[(rep * 16 + t4 + i) * 33 + e4 + j] = acc[i][j];
    __syncthreads();

    for (int p = tid; p < 16 * 32; p += 256) {
        int tok = p >> 5, e = p & 31;
        float s = 0.f;
        #pragma unroll
        for (int r = 0; r < 8; ++r) s += Lp[(r * 16 + tok) * 33 + e];
        gpart[((size_t)blockIdx.y * NTOK + n0 + tok) * NEXP + e] = s;
    }
}

// ---------------- Kernel G2: sum partials, top-4 (registers), scatter ----------------
__global__ __launch_bounds__(256) void topk_scatter(
    const float* __restrict__ gpart,
    int* __restrict__ cnt, int* __restrict__ tok_list, float* __restrict__ gates)
{
    const int tid = threadIdx.x;
    const int n   = blockIdx.x * 256 + tid;

    __shared__ int hist[NEXP];
    __shared__ int bbase[NEXP];
    if (tid < NEXP) hist[tid] = 0;

    float lg[NEXP];
    #pragma unroll
    for (int i = 0; i < 8; ++i) {
        float4 v = *(const float4*)&gpart[(size_t)n * NEXP + i * 4];
        lg[i*4+0] = v.x; lg[i*4+1] = v.y; lg[i*4+2] = v.z; lg[i*4+3] = v.w;
    }
    #pragma unroll
    for (int j = 1; j < 4; ++j)
        #pragma unroll
        for (int i = 0; i < 8; ++i) {
            float4 v = *(const float4*)&gpart[((size_t)j * NTOK + n) * NEXP + i * 4];
            lg[i*4+0] += v.x; lg[i*4+1] += v.y; lg[i*4+2] += v.z; lg[i*4+3] += v.w;
        }

    int sel[TOPK]; float sv[TOPK];
    #pragma unroll
    for (int j = 0; j < TOPK; ++j) {
        float bv = -3.0e38f; int bi = 0;
        #pragma unroll
        for (int e = 0; e < NEXP; ++e) {
            bool taken = false;
            #pragma unroll
            for (int q = 0; q < j; ++q) taken = taken || (sel[q] == e);
            float v = taken ? -3.0e38f : lg[e];
            if (v > bv) { bv = v; bi = e; }   // strict >: lowest idx wins ties
        }
        sel[j] = bi; sv[j] = bv;
    }

    __syncthreads();
    int lpos[TOPK];
    #pragma unroll
    for (int j = 0; j < TOPK; ++j) {
        gates[n * TOPK + j] = 1.f / (1.f + expf(-sv[j]));
        lpos[j] = atomicAdd(&hist[sel[j]], 1);
    }
    __syncthreads();
    if (tid < NEXP) bbase[tid] = atomicAdd(&cnt[tid], hist[tid]);
    __syncthreads();
    #pragma unroll
    for (int j = 0; j < TOPK; ++j)
        tok_list[(size_t)sel[j] * NTOK + bbase[sel[j]] + lpos[j]] = n * TOPK + j;
}

// ---------------- Kernel F: fused expert FFN, 64-slot tiles, 2-deep pipeline ----------------
// Grid = 512 (e = bid&31 pins an expert to one XCD's L2; t0 = bid>>5, tiles stride 16).
// Stage-before-compute with double buffers: ONE __syncthreads per chunk (its implicit
// vmcnt(0) drains loads whose latency was hidden under the chunk's MFMAs).
// LDS pool (ushorts), phase A: buf0[12288]=K(8192)+X(4096) @0, buf1 @12288.
// Phase B: Hs[64*140]=8960 @0 (aliases buf0), V dbuf 2x8192 @12288, OSB dbuf 2x4608 @28672.
__global__ __launch_bounds__(256) void ffn_fused(
    const unsigned short* __restrict__ Xb,   // [N][1024] bf16
    const unsigned short* __restrict__ Kb,   // [E][128][128][8]
    const unsigned short* __restrict__ Vb,   // [E][16][1024][8]
    const int* __restrict__ cnt, const int* __restrict__ tok_list,
    const float* __restrict__ gates,
    unsigned short* __restrict__ Ob)         // [N*4][1024] bf16
{
    const int bid = blockIdx.x;
    const int e = bid & 31, t0 = bid >> 5;
    const int c = cnt[e];
    const int tid  = threadIdx.x, wave = tid >> 6, lane = tid & 63;
    const int lm   = lane & 15, quad = lane >> 4;
    const int r2   = (wave >> 1) * 32;       // 32-row half of the 64-slot tile
    const int c2   = (wave & 1) * 64;        // phase A: 64-col half of 128
    const int cw   = (wave & 1) * 32;        // phase B: 32-col half of 64

    __shared__ __align__(16) unsigned short P[37888];     // 75776 B pool (see layout above)
    __shared__ int slot[64]; __shared__ int gtok[64]; __shared__ float gs[64];

    const unsigned short* Ke = Kb + (size_t)e * 131072;
    const unsigned short* Ve = Vb + (size_t)e * 131072;

    for (int tile = t0; tile * 64 < c; tile += 16) {
        const int base = tile * 64;
        const int nt   = min(64, c - base);

        __syncthreads();                       // protect slot/gtok/gs + buf0 vs prior tile
        if (tid < 64) {
            if (tid < nt) {
                int v = tok_list[(size_t)e * NTOK + base + tid];
                slot[tid] = v; gtok[tid] = v >> 2; gs[tid] = gates[v];
            } else { slot[tid] = -1; gtok[tid] = 0; gs[tid] = 0.f; }
        }
        __syncthreads();

        const unsigned short* xrowb = Xb + (size_t)gtok[lane] * DDIM;   // per-lane token row

        // ---------------- phase A: H[64][128] = relu(X_tile @ K_e) * g ----------------
        f32x4 acc[2][4];
        #pragma unroll
        for (int i = 0; i < 2; ++i)
            #pragma unroll
            for (int j = 0; j < 4; ++j) acc[i][j] = (f32x4){0.f, 0.f, 0.f, 0.f};

        auto stageA = [&](int t, int cb) {
            unsigned short* B = &P[cb * 12288];
            #pragma unroll
            for (int i = 0; i < 4; ++i) {      // K: 16 x 1KB pieces, 4/wave
                int p = wave * 4 + i;
                async_cp16(Ke + ((size_t)(t * 8 + (p >> 1)) * 128 + (p & 1) * 64 + lane) * 8,
                           B + p * 512);
            }
            #pragma unroll
            for (int i = 0; i < 2; ++i) {      // X: 8 x 1KB pieces (row gather), 2/wave
                int k0 = wave * 2 + i;
                async_cp16(xrowb + t * 64 + k0 * 8, B + 8192 + k0 * 512);
            }
        };

        stageA(0, 0);
        __syncthreads();                       // drain prologue

        for (int t = 0; t < 16; ++t) {
            const int cb = t & 1;
            if (t < 15) stageA(t + 1, cb ^ 1); // issue next chunk BEFORE compute
            const unsigned short* B = &P[cb * 12288];
            #pragma unroll
            for (int ks = 0; ks < 2; ++ks) {
                int k0 = ks * 4 + quad;
                bf16x8 a0 = *(const bf16x8*)&B[8192 + (k0 * 64 + r2 + lm) * 8];
                bf16x8 a1 = *(const bf16x8*)&B[8192 + (k0 * 64 + r2 + 16 + lm) * 8];
                #pragma unroll
                for (int tj = 0; tj < 4; ++tj) {
                    bf16x8 bb = *(const bf16x8*)&B[(k0 * 128 + c2 + tj * 16 + lm) * 8];
                    acc[0][tj] = __builtin_amdgcn_mfma_f32_16x16x32_bf16(a0, bb, acc[0][tj], 0, 0, 0);
                    acc[1][tj] = __builtin_amdgcn_mfma_f32_16x16x32_bf16(a1, bb, acc[1][tj], 0, 0, 0);
                }
            }
            __syncthreads();                   // vmcnt(0) drain (hidden) + publish chunk t+1
        }

        // epilogue A: relu * gate -> Hs (row-major [m][140], aliases buf0 -- safe post-barrier)
        #pragma unroll
        for (int ti = 0; ti < 2; ++ti)
            #pragma unroll
            for (int reg = 0; reg < 4; ++reg) {
                int m = r2 + ti * 16 + quad * 4 + reg;
                float g = gs[m];
                #pragma unroll
                for (int tj = 0; tj < 4; ++tj)
                    P[m * 140 + c2 + tj * 16 + lm] = f2bf(fmaxf(acc[ti][tj][reg], 0.f) * g);
            }

        // ---------------- phase B: Ob = H @ V_e ----------------
        auto stageV = [&](int cc, int vb) {
            unsigned short* B = &P[12288 + vb * 8192];
            #pragma unroll
            for (int i = 0; i < 4; ++i) {      // V: 16 x 1KB pieces, 4/wave
                int p = wave * 4 + i;
                async_cp16(Ve + ((size_t)p * 1024 + cc * 64 + lane) * 8, B + p * 512);
            }
        };

        stageV(0, 0);                          // V0 region aliases buf1 (phase A done)
        __syncthreads();                       // Hs visible + V0 drained

        const int om = tid >> 2, oq = tid & 3; // store mapping: 2 uint4/thread
        const int os = slot[om];

        for (int cc = 0; cc < 16; ++cc) {
            const int vb = cc & 1;
            if (cc < 15) stageV(cc + 1, vb ^ 1);   // issue next V chunk BEFORE compute

            f32x4 acc2[2][2];
            #pragma unroll
            for (int i = 0; i < 2; ++i) {
                acc2[i][0] = (f32x4){0.f, 0.f, 0.f, 0.f};
                acc2[i][1] = (f32x4){0.f, 0.f, 0.f, 0.f};
            }

            const unsigned short* B = &P[12288 + vb * 8192];
            #pragma unroll
            for (int ks = 0; ks < 4; ++ks) {
                int k0 = ks * 4 + quad;
                bf16x8 a0 = *(const bf16x8*)&P[(r2 + lm) * 140 + k0 * 8];
                bf16x8 a1 = *(const bf16x8*)&P[(r2 + 16 + lm) * 140 + k0 * 8];
                #pragma unroll
                for (int tj = 0; tj < 2; ++tj) {
                    bf16x8 bb = *(const bf16x8*)&B[(k0 * 64 + cw + tj * 16 + lm) * 8];
                    acc2[0][tj] = __builtin_amdgcn_mfma_f32_16x16x32_bf16(a0, bb, acc2[0][tj], 0, 0, 0);
                    acc2[1][tj] = __builtin_amdgcn_mfma_f32_16x16x32_bf16(a1, bb, acc2[1][tj], 0, 0, 0);
                }
            }

            // bounce C-tile through double-buffered OSB for coalesced 16B stores
            unsigned short* OSB = &P[28672 + vb * 4608];
            #pragma unroll
            for (int ti = 0; ti < 2; ++ti)
                #pragma unroll
                for (int reg = 0; reg < 4; ++reg) {
                    int m = r2 + ti * 16 + quad * 4 + reg;
                    OSB[m * 72 + cw + lm]      = f2bf(acc2[ti][0][reg]);
                    OSB[m * 72 + cw + 16 + lm] = f2bf(acc2[ti][1][reg]);
                }
            __syncthreads();                   // OSB[vb] visible + next V drained

            if (os >= 0) {
                uint4 v0 = *(const uint4*)&OSB[om * 72 + oq * 16];
                uint4 v1 = *(const uint4*)&OSB[om * 72 + oq * 16 + 8];
                unsigned short* op = Ob + (size_t)os * DDIM + cc * 64 + oq * 16;
                *(uint4*)op       = v0;
                *(uint4*)(op + 8) = v1;
            }
        }
    }
}

// ---------------- Kernel R: out[n] = sum_j Ob[4n+j]  (bf16 -> fp32) ----------------
__global__ __launch_bounds__(256) void reduce_out(
    const unsigned short* __restrict__ Ob, float* __restrict__ out)
{
    const int tid = threadIdx.x;
    const int n   = blockIdx.x * 2 + (tid >> 7);
    const int cc  = (tid & 127) * 8;

    float s[8] = {};
    #pragma unroll
    for (int j = 0; j < 4; ++j) {
        uint4 v = *(const uint4*)&Ob[((size_t)n * 4 + j) * DDIM + cc];
        const unsigned int w[4] = {v.x, v.y, v.z, v.w};
        #pragma unroll
        for (int q = 0; q < 4; ++q) {
            s[q * 2 + 0] += bf2f((unsigned short)(w[q] & 0xffff));
            s[q * 2 + 1] += bf2f((unsigned short)(w[q] >> 16));
        }
    }
    float4 o0 = {s[0], s[1], s[2], s[3]};
    float4 o1 = {s[4], s[5], s[6], s[7]};
    *(float4*)&out[(size_t)n * DDIM + cc]     = o0;
    *(float4*)&out[(size_t)n * DDIM + cc + 4] = o1;
}

extern "C" void kernel_launch(void* const* d_in, const int* in_sizes, int n_in,
                              void* d_out, int out_size, void* d_ws, size_t ws_size,
                              hipStream_t stream) {
    const float* x      = (const float*)d_in[0];
    const float* es     = (const float*)d_in[1];
    const float* keys   = (const float*)d_in[2];
    const float* values = (const float*)d_in[3];
    float* out          = (float*)d_out;

    // workspace layout (~105 MB)
    char* w = (char*)d_ws;
    int*   cnt      = (int*)w;               w += 256;
    int*   tok_list = (int*)w;               w += (size_t)NEXP * NTOK * sizeof(int);    // 1 MB
    float* gates    = (float*)w;             w += (size_t)NTOK * TOPK * sizeof(float);  // 128 KB
    float* gpart    = (float*)w;             w += (size_t)4 * NTOK * NEXP * sizeof(float); // 4 MB
    unsigned short* Kb = (unsigned short*)w; w += (size_t)NEXP * 128 * 128 * 8 * 2;     // 8 MB
    unsigned short* Vb = (unsigned short*)w; w += (size_t)NEXP * 16 * 1024 * 8 * 2;     // 8 MB
    unsigned short* Xb = (unsigned short*)w; w += (size_t)NTOK * DDIM * 2;              // 16.8 MB
    unsigned short* Ob = (unsigned short*)w;                                            // 67 MB

    hipMemsetAsync(cnt, 0, NEXP * sizeof(int), stream);

    prep_weights<<<4096, 256, 0, stream>>>(keys, values, Kb, Vb);
    gate_partial<<<dim3(NTOK / 16, 4), 256, 0, stream>>>(x, es, gpart, Xb);
    topk_scatter<<<NTOK / 256, 256, 0, stream>>>(gpart, cnt, tok_list, gates);

    ffn_fused<<<512, 256, 0, stream>>>(Xb, Kb, Vb, cnt, tok_list, gates, Ob);
    reduce_out<<<NTOK / 2, 256, 0, stream>>>(Ob, out);
}

// Round 2
// 226.628 us; speedup vs baseline: 1.0979x; 1.0979x over previous
//
#include <hip/hip_runtime.h>
#include <hip/hip_bf16.h>

#define NTOK 8192   // B*S
#define DDIM 1024
#define NEXP 32
#define HDIM 128
#define TOPK 4

typedef __attribute__((ext_vector_type(8))) short bf16x8;
typedef __attribute__((ext_vector_type(4))) float f32x4;

typedef unsigned int uint_g __attribute__((address_space(1)));
typedef unsigned int uint_l __attribute__((address_space(3)));

// async 16B/lane global->LDS; LDS dest = wave-uniform base + lane*16.
__device__ __forceinline__ void async_cp16(const void* g, void* l) {
    __builtin_amdgcn_global_load_lds((const uint_g*)g, (uint_l*)l, 16, 0, 0);
}

__device__ inline unsigned short f2bf(float f) {
    unsigned int u = __builtin_bit_cast(unsigned int, f);
    unsigned int r = (u + 0x7fffu + ((u >> 16) & 1u)) >> 16;   // RNE
    return (unsigned short)r;
}
__device__ inline float bf2f(unsigned short s) {
    unsigned int u = ((unsigned int)s) << 16;
    return __builtin_bit_cast(float, u);
}

// ---------------- Kernel P: K/V -> bf16 MFMA layout (x handled in gate_partial) ----------------
__global__ __launch_bounds__(256) void prep_weights(
    const float* __restrict__ keys, const float* __restrict__ values,
    unsigned short* __restrict__ Kb, unsigned short* __restrict__ Vb)
{
    int idx = blockIdx.x * 256 + threadIdx.x;
    unsigned short o[8];
    if (idx < NEXP * 128 * 128) {            // keys: (e, k0 [128], n [128])
        int n = idx & 127, k0 = (idx >> 7) & 127, e = idx >> 14;
        const float* s = keys + ((size_t)e * DDIM + k0 * 8) * HDIM + n;
        #pragma unroll
        for (int j = 0; j < 8; ++j) o[j] = f2bf(s[(size_t)j * HDIM]);
        *(uint4*)&Kb[(size_t)idx * 8] = *(uint4*)o;
    } else {                                 // values: (e, k0 [16], n [1024])
        idx -= NEXP * 128 * 128;
        int n = idx & 1023, k0 = (idx >> 10) & 15, e = idx >> 14;
        const float* s = values + ((size_t)e * HDIM + k0 * 8) * DDIM + n;
        #pragma unroll
        for (int j = 0; j < 8; ++j) o[j] = f2bf(s[(size_t)j * DDIM]);
        *(uint4*)&Vb[(size_t)idx * 8] = *(uint4*)o;
    }
}

// ---------------- Kernel G1: gating partial logits (fp32) + fused x->bf16 emit ----------------
__global__ __launch_bounds__(256) void gate_partial(
    const float* __restrict__ x, const float* __restrict__ es,
    float* __restrict__ gpart,               // [4][NTOK][32]
    unsigned short* __restrict__ Xb)         // [NTOK][1024] bf16
{
    const int n0    = blockIdx.x * 16;
    const int dbase = blockIdx.y * 256;
    const int tid   = threadIdx.x;

    __shared__ float smem[4608];             // staging tiles, reused as Lp
    float* Xt  = smem;                       // [d][tok] stride 36
    float* Est = smem + 64 * 36;             // [d][e]   stride 36

    const int t4  = (tid & 3) * 4;
    const int e4  = ((tid >> 2) & 7) * 4;
    const int rep = tid >> 5;

    const int xr = tid & 15, xc4 = (tid >> 4) * 4;
    const int er = tid & 31, ec8 = (tid >> 5) * 8;

    const int ctok = tid >> 4, cd4 = (tid & 15) * 4;   // x->bf16 emit mapping

    float acc[4][4] = {};

    for (int dc = dbase; dc < dbase + 256; dc += 64) {
        __syncthreads();
        {
            float4 v = *(const float4*)&x[(size_t)(n0 + xr) * DDIM + dc + xc4];
            Xt[(xc4 + 0) * 36 + xr] = v.x; Xt[(xc4 + 1) * 36 + xr] = v.y;
            Xt[(xc4 + 2) * 36 + xr] = v.z; Xt[(xc4 + 3) * 36 + xr] = v.w;
        }
        #pragma unroll
        for (int i = 0; i < 2; ++i) {
            float4 v = *(const float4*)&es[(size_t)er * DDIM + dc + ec8 + i * 4];
            Est[(ec8 + i * 4 + 0) * 36 + er] = v.x;
            Est[(ec8 + i * 4 + 1) * 36 + er] = v.y;
            Est[(ec8 + i * 4 + 2) * 36 + er] = v.z;
            Est[(ec8 + i * 4 + 3) * 36 + er] = v.w;
        }
        __syncthreads();

        // fused: emit this x tile as bf16 (each thread 4 contiguous elems of one row)
        {
            unsigned short o[4];
            #pragma unroll
            for (int j = 0; j < 4; ++j) o[j] = f2bf(Xt[(cd4 + j) * 36 + ctok]);
            *(uint2*)&Xb[(size_t)(n0 + ctok) * DDIM + dc + cd4] = *(uint2*)o;
        }

        #pragma unroll
        for (int s = 0; s < 8; ++s) {
            int d = s * 8 + rep;
            float4 xv = *(const float4*)&Xt[d * 36 + t4];
            float4 ev = *(const float4*)&Est[d * 36 + e4];
            const float xa[4] = {xv.x, xv.y, xv.z, xv.w};
            const float ea[4] = {ev.x, ev.y, ev.z, ev.w};
            #pragma unroll
            for (int i = 0; i < 4; ++i)
                #pragma unroll
                for (int j = 0; j < 4; ++j)
                    acc[i][j] = fmaf(xa[i], ea[j], acc[i][j]);
        }
    }

    __syncthreads();
    float* Lp = smem;                         // [rep 8][tok 16][e 33]
    #pragma unroll
    for (int i = 0; i < 4; ++i)
        #pragma unroll
        for (int j = 0; j < 4; ++j)
            Lp[(rep * 16 + t4 + i) * 33 + e4 + j] = acc[i][j];
    __syncthreads();

    for (int p = tid; p < 16 * 32; p += 256) {
        int tok = p >> 5, e = p & 31;
        float s = 0.f;
        #pragma unroll
        for (int r = 0; r < 8; ++r) s += Lp[(r * 16 + tok) * 33 + e];
        gpart[((size_t)blockIdx.y * NTOK + n0 + tok) * NEXP + e] = s;
    }
}

// ---------------- Kernel G2: sum partials, top-4 (registers), scatter ----------------
__global__ __launch_bounds__(256) void topk_scatter(
    const float* __restrict__ gpart,
    int* __restrict__ cnt, int* __restrict__ tok_list, float* __restrict__ gates)
{
    const int tid = threadIdx.x;
    const int n   = blockIdx.x * 256 + tid;

    __shared__ int hist[NEXP];
    __shared__ int bbase[NEXP];
    if (tid < NEXP) hist[tid] = 0;

    float lg[NEXP];
    #pragma unroll
    for (int i = 0; i < 8; ++i) {
        float4 v = *(const float4*)&gpart[(size_t)n * NEXP + i * 4];
        lg[i*4+0] = v.x; lg[i*4+1] = v.y; lg[i*4+2] = v.z; lg[i*4+3] = v.w;
    }
    #pragma unroll
    for (int j = 1; j < 4; ++j)
        #pragma unroll
        for (int i = 0; i < 8; ++i) {
            float4 v = *(const float4*)&gpart[((size_t)j * NTOK + n) * NEXP + i * 4];
            lg[i*4+0] += v.x; lg[i*4+1] += v.y; lg[i*4+2] += v.z; lg[i*4+3] += v.w;
        }

    int sel[TOPK]; float sv[TOPK];
    #pragma unroll
    for (int j = 0; j < TOPK; ++j) {
        float bv = -3.0e38f; int bi = 0;
        #pragma unroll
        for (int e = 0; e < NEXP; ++e) {
            bool taken = false;
            #pragma unroll
            for (int q = 0; q < j; ++q) taken = taken || (sel[q] == e);
            float v = taken ? -3.0e38f : lg[e];
            if (v > bv) { bv = v; bi = e; }   // strict >: lowest idx wins ties
        }
        sel[j] = bi; sv[j] = bv;
    }

    __syncthreads();
    int lpos[TOPK];
    #pragma unroll
    for (int j = 0; j < TOPK; ++j) {
        gates[n * TOPK + j] = 1.f / (1.f + expf(-sv[j]));
        lpos[j] = atomicAdd(&hist[sel[j]], 1);
    }
    __syncthreads();
    if (tid < NEXP) bbase[tid] = atomicAdd(&cnt[tid], hist[tid]);
    __syncthreads();
    #pragma unroll
    for (int j = 0; j < TOPK; ++j)
        tok_list[(size_t)sel[j] * NTOK + bbase[sel[j]] + lpos[j]] = n * TOPK + j;
}

// ---------------- Kernel F: fused expert FFN, 64-slot tiles ----------------
// Grid 4096 (one tile/block, early exit -> scheduler refill + balance).
// Operand-swapped MFMAs throughout:
//   phase A: C' = mfma(K_frag, X_frag)  -> C' rows = n, cols = tok.
//            X fragments load straight global->VGPR (no LDS), reg-double-buffered.
//            K double-buffered in LDS (2 x 16 KB), ONE barrier per chunk.
//   phase B: C' = mfma(V_frag, H_frag)  -> C' rows = d, cols = tok.
//            Direct 8B/lane stores to Ob (no OSB bounce), H frags hoisted to regs,
//            V double-buffered reusing the K buffers, ONE barrier per chunk.
// LDS = 32 KB (KV dbuf) + 17.9 KB (Hs) + 0.75 KB ≈ 51.5 KB -> 3 blocks/CU.
__global__ __launch_bounds__(256) void ffn_fused(
    const unsigned short* __restrict__ Xb,   // [N][1024] bf16
    const unsigned short* __restrict__ Kb,   // [E][128][128][8]
    const unsigned short* __restrict__ Vb,   // [E][16][1024][8]
    const int* __restrict__ cnt, const int* __restrict__ tok_list,
    const float* __restrict__ gates,
    unsigned short* __restrict__ Ob)         // [N*4][1024] bf16
{
    const int bid = blockIdx.x;
    const int e = bid & 31, tile = bid >> 5;
    const int c = cnt[e], base = tile * 64;
    if (base >= c) return;
    const int nt   = min(64, c - base);
    const int tid  = threadIdx.x, wave = tid >> 6, lane = tid & 63;
    const int lm   = lane & 15, quad = lane >> 4;
    const int r2   = (wave >> 1) * 32;       // token half (32 rows of the 64-slot tile)
    const int c2   = (wave & 1) * 64;        // phase A: n half (64 of 128)
    const int dw   = (wave & 1) * 32;        // phase B: d half (32 of 64)

    __shared__ __align__(16) unsigned short KV[2][8192];  // 32 KB: K chunks / V chunks dbuf
    __shared__ __align__(16) unsigned short Hs[64 * 140]; // 17.9 KB (280B stride = conflict-benign)
    __shared__ int slot[64]; __shared__ int gtok[64]; __shared__ float gs[64];

    if (tid < 64) {
        if (tid < nt) {
            int v = tok_list[(size_t)e * NTOK + base + tid];
            slot[tid] = v; gtok[tid] = v >> 2; gs[tid] = gates[v];
        } else { slot[tid] = -1; gtok[tid] = 0; gs[tid] = 0.f; }
    }
    __syncthreads();

    const unsigned short* Ke  = Kb + (size_t)e * 131072;
    const unsigned short* Ve  = Vb + (size_t)e * 131072;
    // per-lane X row pointers for the two token sub-tiles (quad offset baked in)
    const unsigned short* xp0 = Xb + (size_t)gtok[r2 + lm]      * DDIM + quad * 8;
    const unsigned short* xp1 = Xb + (size_t)gtok[r2 + 16 + lm] * DDIM + quad * 8;

    auto stageK = [&](int t, int cb) {
        #pragma unroll
        for (int i = 0; i < 4; ++i) {          // K chunk: 16 x 1KB pieces, 4/wave
            int p = wave * 4 + i;
            async_cp16(Ke + ((size_t)(t * 8 + (p >> 1)) * 128 + (p & 1) * 64 + lane) * 8,
                       &KV[cb][p * 512]);
        }
    };
    auto stageV = [&](int cc, int vb) {
        #pragma unroll
        for (int i = 0; i < 4; ++i) {          // V chunk: 16 x 1KB pieces, 4/wave
            int p = wave * 4 + i;
            async_cp16(Ve + ((size_t)p * 1024 + cc * 64 + lane) * 8, &KV[vb][p * 512]);
        }
    };

    // ---------------- phase A: H^T = K^T X^T, acc C' rows=n cols=tok ----------------
    f32x4 acc[2][4];
    #pragma unroll
    for (int i = 0; i < 2; ++i)
        #pragma unroll
        for (int j = 0; j < 4; ++j) acc[i][j] = (f32x4){0.f, 0.f, 0.f, 0.f};

    bf16x8 xA[2][2], xB[2][2];                 // [tt][ks] reg double-buffer for X frags

    stageK(0, 0);
    #pragma unroll
    for (int ks = 0; ks < 2; ++ks) {
        xA[0][ks] = *(const bf16x8*)&xp0[ks * 32];
        xA[1][ks] = *(const bf16x8*)&xp1[ks * 32];
    }
    __syncthreads();                           // drain prologue

    auto achunk = [&](int t, bf16x8 (&xc)[2][2], bf16x8 (&xn)[2][2], int cb) {
        if (t < 15) {
            stageK(t + 1, cb ^ 1);             // issue next K chunk (async -> other buffer)
            #pragma unroll
            for (int ks = 0; ks < 2; ++ks) {   // prefetch next X frags into regs
                xn[0][ks] = *(const bf16x8*)&xp0[(t + 1) * 64 + ks * 32];
                xn[1][ks] = *(const bf16x8*)&xp1[(t + 1) * 64 + ks * 32];
            }
        } else {
            stageV(0, 0);                      // A->B transition prefetch (buf0 free: t=15 reads buf1)
        }
        #pragma unroll
        for (int ks = 0; ks < 2; ++ks)
            #pragma unroll
            for (int tn = 0; tn < 4; ++tn) {
                const int k0 = ks * 4 + quad;
                bf16x8 kf = *(const bf16x8*)&KV[cb][(k0 * 128 + c2 + tn * 16 + lm) * 8];
                acc[0][tn] = __builtin_amdgcn_mfma_f32_16x16x32_bf16(kf, xc[0][ks], acc[0][tn], 0, 0, 0);
                acc[1][tn] = __builtin_amdgcn_mfma_f32_16x16x32_bf16(kf, xc[1][ks], acc[1][tn], 0, 0, 0);
            }
        __syncthreads();                       // one barrier/chunk (drain hidden under compute)
    };

    for (int th = 0; th < 8; ++th) {
        achunk(th * 2,     xA, xB, 0);
        achunk(th * 2 + 1, xB, xA, 1);
    }

    // epilogue A: relu * gate -> Hs[tok][n], 8B ds_writes (C' lane holds 4 consecutive n)
    #pragma unroll
    for (int tt = 0; tt < 2; ++tt) {
        float g = gs[r2 + tt * 16 + lm];
        #pragma unroll
        for (int tn = 0; tn < 4; ++tn) {
            unsigned short o[4];
            #pragma unroll
            for (int r = 0; r < 4; ++r) o[r] = f2bf(fmaxf(acc[tt][tn][r], 0.f) * g);
            *(uint2*)&Hs[(r2 + tt * 16 + lm) * 140 + c2 + tn * 16 + quad * 4] = *(uint2*)o;
        }
    }
    __syncthreads();                           // Hs visible (V chunk 0 already drained)

    // ---------------- phase B: O = H V, C' rows=d cols=tok ----------------
    // hoist H fragments (B-operand) to registers: read LDS once, not per chunk
    bf16x8 hf[2][4];                           // [tt][ks]
    #pragma unroll
    for (int tt = 0; tt < 2; ++tt)
        #pragma unroll
        for (int ks = 0; ks < 4; ++ks)
            hf[tt][ks] = *(const bf16x8*)&Hs[(r2 + tt * 16 + lm) * 140 + (ks * 4 + quad) * 8];

    const int s0 = slot[r2 + lm], s1 = slot[r2 + 16 + lm];

    for (int cc = 0; cc < 16; ++cc) {
        const int vb = cc & 1;
        if (cc < 15) stageV(cc + 1, vb ^ 1);   // issue next V chunk before compute

        f32x4 acc2[2][2];
        #pragma unroll
        for (int i = 0; i < 2; ++i) {
            acc2[i][0] = (f32x4){0.f, 0.f, 0.f, 0.f};
            acc2[i][1] = (f32x4){0.f, 0.f, 0.f, 0.f};
        }

        #pragma unroll
        for (int ks = 0; ks < 4; ++ks) {
            const int k0 = ks * 4 + quad;
            #pragma unroll
            for (int td = 0; td < 2; ++td) {
                bf16x8 vf = *(const bf16x8*)&KV[vb][(k0 * 64 + dw + td * 16 + lm) * 8];
                acc2[0][td] = __builtin_amdgcn_mfma_f32_16x16x32_bf16(vf, hf[0][ks], acc2[0][td], 0, 0, 0);
                acc2[1][td] = __builtin_amdgcn_mfma_f32_16x16x32_bf16(vf, hf[1][ks], acc2[1][td], 0, 0, 0);
            }
        }
        __syncthreads();                       // drain next V; all reads of KV[vb] done

        // direct stores: lane holds 4 consecutive d per tile -> 8B store; store-ack
        // latency hides under the NEXT chunk's compute (stores placed after barrier)
        if (s0 >= 0) {
            #pragma unroll
            for (int td = 0; td < 2; ++td) {
                unsigned short o[4];
                #pragma unroll
                for (int r = 0; r < 4; ++r) o[r] = f2bf(acc2[0][td][r]);
                *(uint2*)&Ob[(size_t)s0 * DDIM + cc * 64 + dw + td * 16 + quad * 4] = *(uint2*)o;
            }
        }
        if (s1 >= 0) {
            #pragma unroll
            for (int td = 0; td < 2; ++td) {
                unsigned short o[4];
                #pragma unroll
                for (int r = 0; r < 4; ++r) o[r] = f2bf(acc2[1][td][r]);
                *(uint2*)&Ob[(size_t)s1 * DDIM + cc * 64 + dw + td * 16 + quad * 4] = *(uint2*)o;
            }
        }
    }
}

// ---------------- Kernel R: out[n] = sum_j Ob[4n+j]  (bf16 -> fp32) ----------------
__global__ __launch_bounds__(256) void reduce_out(
    const unsigned short* __restrict__ Ob, float* __restrict__ out)
{
    const int tid = threadIdx.x;
    const int n   = blockIdx.x * 2 + (tid >> 7);
    const int cc  = (tid & 127) * 8;

    float s[8] = {};
    #pragma unroll
    for (int j = 0; j < 4; ++j) {
        uint4 v = *(const uint4*)&Ob[((size_t)n * 4 + j) * DDIM + cc];
        const unsigned int w[4] = {v.x, v.y, v.z, v.w};
        #pragma unroll
        for (int q = 0; q < 4; ++q) {
            s[q * 2 + 0] += bf2f((unsigned short)(w[q] & 0xffff));
            s[q * 2 + 1] += bf2f((unsigned short)(w[q] >> 16));
        }
    }
    float4 o0 = {s[0], s[1], s[2], s[3]};
    float4 o1 = {s[4], s[5], s[6], s[7]};
    *(float4*)&out[(size_t)n * DDIM + cc]     = o0;
    *(float4*)&out[(size_t)n * DDIM + cc + 4] = o1;
}

extern "C" void kernel_launch(void* const* d_in, const int* in_sizes, int n_in,
                              void* d_out, int out_size, void* d_ws, size_t ws_size,
                              hipStream_t stream) {
    const float* x      = (const float*)d_in[0];
    const float* es     = (const float*)d_in[1];
    const float* keys   = (const float*)d_in[2];
    const float* values = (const float*)d_in[3];
    float* out          = (float*)d_out;

    // workspace layout (~105 MB)
    char* w = (char*)d_ws;
    int*   cnt      = (int*)w;               w += 256;
    int*   tok_list = (int*)w;               w += (size_t)NEXP * NTOK * sizeof(int);    // 1 MB
    float* gates    = (float*)w;             w += (size_t)NTOK * TOPK * sizeof(float);  // 128 KB
    float* gpart    = (float*)w;             w += (size_t)4 * NTOK * NEXP * sizeof(float); // 4 MB
    unsigned short* Kb = (unsigned short*)w; w += (size_t)NEXP * 128 * 128 * 8 * 2;     // 8 MB
    unsigned short* Vb = (unsigned short*)w; w += (size_t)NEXP * 16 * 1024 * 8 * 2;     // 8 MB
    unsigned short* Xb = (unsigned short*)w; w += (size_t)NTOK * DDIM * 2;              // 16.8 MB
    unsigned short* Ob = (unsigned short*)w;                                            // 67 MB

    hipMemsetAsync(cnt, 0, NEXP * sizeof(int), stream);

    prep_weights<<<4096, 256, 0, stream>>>(keys, values, Kb, Vb);
    gate_partial<<<dim3(NTOK / 16, 4), 256, 0, stream>>>(x, es, gpart, Xb);
    topk_scatter<<<NTOK / 256, 256, 0, stream>>>(gpart, cnt, tok_list, gates);

    ffn_fused<<<128 * NEXP, 256, 0, stream>>>(Xb, Kb, Vb, cnt, tok_list, gates, Ob);
    reduce_out<<<NTOK / 2, 256, 0, stream>>>(Ob, out);
}

// Round 6
// 213.304 us; speedup vs baseline: 1.1664x; 1.0625x over previous
//
#include <hip/hip_runtime.h>
#include <hip/hip_bf16.h>

#define NTOK 8192   // B*S
#define DDIM 1024
#define NEXP 32
#define HDIM 128
#define TOPK 4

typedef __attribute__((ext_vector_type(8))) short bf16x8;
typedef __attribute__((ext_vector_type(4))) float f32x4;

typedef unsigned int uint_g __attribute__((address_space(1)));
typedef unsigned int uint_l __attribute__((address_space(3)));

// async 16B/lane global->LDS; LDS dest = wave-uniform base + lane*16.
__device__ __forceinline__ void async_cp16(const void* g, void* l) {
    __builtin_amdgcn_global_load_lds((const uint_g*)g, (uint_l*)l, 16, 0, 0);
}

__device__ inline unsigned short f2bf(float f) {
    unsigned int u = __builtin_bit_cast(unsigned int, f);
    unsigned int r = (u + 0x7fffu + ((u >> 16) & 1u)) >> 16;   // RNE
    return (unsigned short)r;
}
__device__ inline float bf2f(unsigned short s) {
    unsigned int u = ((unsigned int)s) << 16;
    return __builtin_bit_cast(float, u);
}

// ---------------- Kernel PG: fused prep (K/V->bf16) + gating + top-4 + scatter ----------------
// grid = 4096 prep-blocks + 512 gate-blocks (16 tokens each, full D).
// Gating arithmetic reproduces the R2-verified order EXACTLY: per quarter q,
// acc over 4x64-dim chunks -> Lp -> 8-rep reduce; quarter partials summed in q order.
__global__ __launch_bounds__(256) void prep_gate(
    const float* __restrict__ x, const float* __restrict__ es,
    const float* __restrict__ keys, const float* __restrict__ values,
    unsigned short* __restrict__ Kb, unsigned short* __restrict__ Vb,
    unsigned short* __restrict__ Xb,
    int* __restrict__ cnt, int* __restrict__ tok_list, float* __restrict__ gates)
{
    const int tid = threadIdx.x;

    if (blockIdx.x < 4096) {                 // ---- prep part (no barriers) ----
        int idx = blockIdx.x * 256 + tid;
        unsigned short o[8];
        if (idx < NEXP * 128 * 128) {        // keys: (e, k0 [128], n [128])
            int n = idx & 127, k0 = (idx >> 7) & 127, e = idx >> 14;
            const float* s = keys + ((size_t)e * DDIM + k0 * 8) * HDIM + n;
            #pragma unroll
            for (int j = 0; j < 8; ++j) o[j] = f2bf(s[(size_t)j * HDIM]);
            *(uint4*)&Kb[(size_t)idx * 8] = *(uint4*)o;
        } else {                             // values: (e, k0 [16], n [1024])
            idx -= NEXP * 128 * 128;
            int n = idx & 1023, k0 = (idx >> 10) & 15, e = idx >> 14;
            const float* s = values + ((size_t)e * HDIM + k0 * 8) * DDIM + n;
            #pragma unroll
            for (int j = 0; j < 8; ++j) o[j] = f2bf(s[(size_t)j * DDIM]);
            *(uint4*)&Vb[(size_t)idx * 8] = *(uint4*)o;
        }
        return;
    }

    // ---- gate part: 16 tokens, full D=1024, fused x->bf16 emit + top-4 + scatter ----
    const int n0 = (int)(blockIdx.x - 4096) * 16;

    __shared__ float smem[4608];             // staging tiles, reused as Lp each quarter
    __shared__ float Ls[16 * 33];            // final logits
    __shared__ int hist[NEXP];
    __shared__ int bbase[NEXP];
    float* Xt  = smem;                       // [d][tok] stride 36
    float* Est = smem + 64 * 36;             // [d][e]   stride 36
    float* Lp  = smem;                       // [rep 8][tok 16][e 33]

    const int t4  = (tid & 3) * 4;
    const int e4  = ((tid >> 2) & 7) * 4;
    const int rep = tid >> 5;

    const int xr = tid & 15, xc4 = (tid >> 4) * 4;
    const int er = tid & 31, ec8 = (tid >> 5) * 8;

    const int ctok = tid >> 4, cd4 = (tid & 15) * 4;   // x->bf16 emit mapping

    // reduce pairs (same as R2's p = tid, tid+256): (tok, e) and (tok+8, e)
    const int rtok = tid >> 5, re = tid & 31;

    float lsum[2] = {0.f, 0.f};

    if (tid < NEXP) hist[tid] = 0;

    for (int q = 0; q < 4; ++q) {
        float acc[4][4] = {};

        for (int dc = q * 256; dc < q * 256 + 256; dc += 64) {
            __syncthreads();                 // prev Xt/Est (or Lp) reads done
            {
                float4 v = *(const float4*)&x[(size_t)(n0 + xr) * DDIM + dc + xc4];
                Xt[(xc4 + 0) * 36 + xr] = v.x; Xt[(xc4 + 1) * 36 + xr] = v.y;
                Xt[(xc4 + 2) * 36 + xr] = v.z; Xt[(xc4 + 3) * 36 + xr] = v.w;
            }
            #pragma unroll
            for (int i = 0; i < 2; ++i) {
                float4 v = *(const float4*)&es[(size_t)er * DDIM + dc + ec8 + i * 4];
                Est[(ec8 + i * 4 + 0) * 36 + er] = v.x;
                Est[(ec8 + i * 4 + 1) * 36 + er] = v.y;
                Est[(ec8 + i * 4 + 2) * 36 + er] = v.z;
                Est[(ec8 + i * 4 + 3) * 36 + er] = v.w;
            }
            __syncthreads();

            // fused: emit this x tile as bf16 (each thread 4 contiguous elems of one row)
            {
                unsigned short o[4];
                #pragma unroll
                for (int j = 0; j < 4; ++j) o[j] = f2bf(Xt[(cd4 + j) * 36 + ctok]);
                *(uint2*)&Xb[(size_t)(n0 + ctok) * DDIM + dc + cd4] = *(uint2*)o;
            }

            #pragma unroll
            for (int s = 0; s < 8; ++s) {
                int d = s * 8 + rep;
                float4 xv = *(const float4*)&Xt[d * 36 + t4];
                float4 ev = *(const float4*)&Est[d * 36 + e4];
                const float xa[4] = {xv.x, xv.y, xv.z, xv.w};
                const float ea[4] = {ev.x, ev.y, ev.z, ev.w};
                #pragma unroll
                for (int i = 0; i < 4; ++i)
                    #pragma unroll
                    for (int j = 0; j < 4; ++j)
                        acc[i][j] = fmaf(xa[i], ea[j], acc[i][j]);
            }
        }

        __syncthreads();                     // Xt/Est reads done; smem -> Lp
        #pragma unroll
        for (int i = 0; i < 4; ++i)
            #pragma unroll
            for (int j = 0; j < 4; ++j)
                Lp[(rep * 16 + t4 + i) * 33 + e4 + j] = acc[i][j];
        __syncthreads();

        #pragma unroll
        for (int h = 0; h < 2; ++h) {        // same reduction order as R2 (r = 0..7)
            int tok = rtok + h * 8;
            float s = 0.f;
            #pragma unroll
            for (int r = 0; r < 8; ++r) s += Lp[(r * 16 + tok) * 33 + re];
            lsum[h] += s;                    // quarter partials summed in q order (R2 topk order)
        }
    }

    #pragma unroll
    for (int h = 0; h < 2; ++h) Ls[(rtok + h * 8) * 33 + re] = lsum[h];
    __syncthreads();

    int sel[TOPK]; int lpos[TOPK];
    if (tid < 16) {
        float lg[NEXP];
        #pragma unroll
        for (int e2 = 0; e2 < NEXP; ++e2) lg[e2] = Ls[tid * 33 + e2];
        float sv[TOPK];
        #pragma unroll
        for (int j = 0; j < TOPK; ++j) {
            float bv = -3.0e38f; int bi = 0;
            #pragma unroll
            for (int e2 = 0; e2 < NEXP; ++e2) {
                bool taken = false;
                #pragma unroll
                for (int q = 0; q < j; ++q) taken = taken || (sel[q] == e2);
                float v = taken ? -3.0e38f : lg[e2];
                if (v > bv) { bv = v; bi = e2; }   // strict >: lowest idx wins ties
            }
            sel[j] = bi; sv[j] = bv;
        }
        #pragma unroll
        for (int j = 0; j < TOPK; ++j) {
            gates[(size_t)(n0 + tid) * TOPK + j] = 1.f / (1.f + expf(-sv[j]));
            lpos[j] = atomicAdd(&hist[sel[j]], 1);
        }
    }
    __syncthreads();
    if (tid < NEXP) bbase[tid] = atomicAdd(&cnt[tid], hist[tid]);
    __syncthreads();
    if (tid < 16) {
        #pragma unroll
        for (int j = 0; j < TOPK; ++j)
            tok_list[(size_t)sel[j] * NTOK + bbase[sel[j]] + lpos[j]] = (n0 + tid) * TOPK + j;
    }
}

// ---------------- Kernel F: fused expert FFN, 64-slot tiles ----------------
// VERBATIM copy of the R0 harness-verified kernel (passed, 53.5 us/dispatch).
// 1-D grid, bid -> (e = bid&31, tile = bid>>5): expert pinned to one XCD's L2.
// Phase A: H[64][128] = relu(X@K_e)*g into LDS (stride 140, 16-bank pattern).
// Phase B: Ob = H @ V_e, V streamed in 64-col chunks through the same 16 KB buffer;
// C-tile bounced through LDS for coalesced uint4 stores.  16 MFMA/wave per chunk.
__global__ __launch_bounds__(256) void ffn_fused(
    const unsigned short* __restrict__ Xb,   // [N][1024] bf16
    const unsigned short* __restrict__ Kb,   // [E][128][128][8]
    const unsigned short* __restrict__ Vb,   // [E][16][1024][8]
    const int* __restrict__ cnt, const int* __restrict__ tok_list,
    const float* __restrict__ gates,
    unsigned short* __restrict__ Ob)         // [N*4][1024] bf16
{
    const int bid = blockIdx.x;
    const int e = bid & 31, tile = bid >> 5;
    const int c = cnt[e], base = tile * 64;
    if (base >= c) return;
    const int nt   = min(64, c - base);
    const int tid  = threadIdx.x, wave = tid >> 6, lane = tid & 63;
    const int lm   = lane & 15, quad = lane >> 4;
    const int r2   = (wave >> 1) * 32;       // 32-row half of the 64-slot tile
    const int c2   = (wave & 1) * 64;        // phase A: 64-col half of 128
    const int cw   = (wave & 1) * 32;        // phase B: 32-col half of 64

    __shared__ __align__(16) unsigned short KV[8192];     // 16 KB: K[8][128][8] | V[16][64][8]
    __shared__ __align__(16) unsigned short XO[4608];     // 9.2 KB: A: Xs[8][64][8] | B: OSB[64][72]
    __shared__ __align__(16) unsigned short Hs[64 * 140]; // 17.9 KB (stride 140 -> 16 banks)
    __shared__ int slot[64]; __shared__ int gtok[64]; __shared__ float gs[64];

    if (tid < 64) {
        if (tid < nt) {
            int v = tok_list[(size_t)e * NTOK + base + tid];
            slot[tid] = v; gtok[tid] = v >> 2; gs[tid] = gates[v];
        } else { slot[tid] = -1; gtok[tid] = 0; gs[tid] = 0.f; }
    }
    __syncthreads();

    const unsigned short* Ke    = Kb + (size_t)e * 131072;
    const unsigned short* Ve    = Vb + (size_t)e * 131072;
    const unsigned short* xrowb = Xb + (size_t)gtok[lane] * DDIM;   // per-lane token row

    // ---------------- phase A: H[64][128] = X_tile @ K_e ----------------
    f32x4 acc[2][4];
    #pragma unroll
    for (int i = 0; i < 2; ++i)
        #pragma unroll
        for (int j = 0; j < 4; ++j) acc[i][j] = (f32x4){0.f, 0.f, 0.f, 0.f};

    auto stageA = [&](int t) {
        int dc = t * 64;
        #pragma unroll
        for (int i = 0; i < 4; ++i) {          // K: 16 x 1KB pieces, 4/wave
            int p = wave * 4 + i;
            async_cp16(Ke + ((size_t)(dc / 8 + (p >> 1)) * 128 + (p & 1) * 64 + lane) * 8,
                       &KV[p * 512]);
        }
        #pragma unroll
        for (int i = 0; i < 2; ++i) {          // X: 8 x 1KB pieces (row gather), 2/wave
            int k0 = wave * 2 + i;
            async_cp16(xrowb + dc + k0 * 8, &XO[k0 * 512]);
        }
    };

    stageA(0);
    __syncthreads();                           // drain

    for (int t = 0; t < 16; ++t) {
        #pragma unroll
        for (int ks = 0; ks < 2; ++ks) {
            int k0 = ks * 4 + quad;
            bf16x8 a0 = *(const bf16x8*)&XO[(k0 * 64 + r2 + lm) * 8];
            bf16x8 a1 = *(const bf16x8*)&XO[(k0 * 64 + r2 + 16 + lm) * 8];
            #pragma unroll
            for (int tj = 0; tj < 4; ++tj) {
                bf16x8 bb = *(const bf16x8*)&KV[(k0 * 128 + c2 + tj * 16 + lm) * 8];
                acc[0][tj] = __builtin_amdgcn_mfma_f32_16x16x32_bf16(a0, bb, acc[0][tj], 0, 0, 0);
                acc[1][tj] = __builtin_amdgcn_mfma_f32_16x16x32_bf16(a1, bb, acc[1][tj], 0, 0, 0);
            }
        }
        if (t < 15) {
            __syncthreads();                   // all reads of chunk t done
            stageA(t + 1);
            __syncthreads();                   // drain chunk t+1
        }
    }

    // epilogue A: relu * gate -> Hs (row-major [m][140])
    #pragma unroll
    for (int ti = 0; ti < 2; ++ti)
        #pragma unroll
        for (int reg = 0; reg < 4; ++reg) {
            int m = r2 + ti * 16 + quad * 4 + reg;
            float g = gs[m];
            #pragma unroll
            for (int tj = 0; tj < 4; ++tj)
                Hs[m * 140 + c2 + tj * 16 + lm] = f2bf(fmaxf(acc[ti][tj][reg], 0.f) * g);
        }
    __syncthreads();                           // Hs complete; KV/XO phase-A reads done

    // ---------------- phase B: Ob = H @ V_e ----------------
    auto stageV = [&](int cc) {
        #pragma unroll
        for (int i = 0; i < 4; ++i) {          // V: 16 x 1KB pieces, 4/wave
            int p = wave * 4 + i;
            async_cp16(Ve + ((size_t)p * 1024 + cc * 64 + lane) * 8, &KV[p * 512]);
        }
    };

    stageV(0);
    __syncthreads();                           // drain

    const int om = tid >> 2, oq = tid & 3;     // store mapping: 2 uint4/thread
    const int os = slot[om];

    for (int cc = 0; cc < 16; ++cc) {
        f32x4 acc2[2][2];
        #pragma unroll
        for (int i = 0; i < 2; ++i) {
            acc2[i][0] = (f32x4){0.f, 0.f, 0.f, 0.f};
            acc2[i][1] = (f32x4){0.f, 0.f, 0.f, 0.f};
        }

        #pragma unroll
        for (int ks = 0; ks < 4; ++ks) {
            int k0 = ks * 4 + quad;
            bf16x8 a0 = *(const bf16x8*)&Hs[(r2 + lm) * 140 + k0 * 8];
            bf16x8 a1 = *(const bf16x8*)&Hs[(r2 + 16 + lm) * 140 + k0 * 8];
            #pragma unroll
            for (int tj = 0; tj < 2; ++tj) {
                bf16x8 bb = *(const bf16x8*)&KV[(k0 * 64 + cw + tj * 16 + lm) * 8];
                acc2[0][tj] = __builtin_amdgcn_mfma_f32_16x16x32_bf16(a0, bb, acc2[0][tj], 0, 0, 0);
                acc2[1][tj] = __builtin_amdgcn_mfma_f32_16x16x32_bf16(a1, bb, acc2[1][tj], 0, 0, 0);
            }
        }

        // bounce C-tile through LDS (OSB[64][72]) for coalesced 16B stores
        #pragma unroll
        for (int ti = 0; ti < 2; ++ti)
            #pragma unroll
            for (int reg = 0; reg < 4; ++reg) {
                int m = r2 + ti * 16 + quad * 4 + reg;
                XO[m * 72 + cw + lm]      = f2bf(acc2[ti][0][reg]);
                XO[m * 72 + cw + 16 + lm] = f2bf(acc2[ti][1][reg]);
            }
        __syncthreads();                       // OSB complete; KV reads done

        if (os >= 0) {
            uint4 v0 = *(const uint4*)&XO[om * 72 + oq * 16];
            uint4 v1 = *(const uint4*)&XO[om * 72 + oq * 16 + 8];
            unsigned short* op = Ob + (size_t)os * DDIM + cc * 64 + oq * 16;
            *(uint4*)op       = v0;
            *(uint4*)(op + 8) = v1;
        }
        if (cc < 15) stageV(cc + 1);
        __syncthreads();                       // drain async; OSB reads done
    }
}

// ---------------- Kernel R: out[n] = sum_j Ob[4n+j]  (bf16 -> fp32) ----------------
__global__ __launch_bounds__(256) void reduce_out(
    const unsigned short* __restrict__ Ob, float* __restrict__ out)
{
    const int tid = threadIdx.x;
    const int n   = blockIdx.x * 2 + (tid >> 7);
    const int cc  = (tid & 127) * 8;

    float s[8] = {};
    #pragma unroll
    for (int j = 0; j < 4; ++j) {
        uint4 v = *(const uint4*)&Ob[((size_t)n * 4 + j) * DDIM + cc];
        const unsigned int w[4] = {v.x, v.y, v.z, v.w};
        #pragma unroll
        for (int q = 0; q < 4; ++q) {
            s[q * 2 + 0] += bf2f((unsigned short)(w[q] & 0xffff));
            s[q * 2 + 1] += bf2f((unsigned short)(w[q] >> 16));
        }
    }
    float4 o0 = {s[0], s[1], s[2], s[3]};
    float4 o1 = {s[4], s[5], s[6], s[7]};
    *(float4*)&out[(size_t)n * DDIM + cc]     = o0;
    *(float4*)&out[(size_t)n * DDIM + cc + 4] = o1;
}

extern "C" void kernel_launch(void* const* d_in, const int* in_sizes, int n_in,
                              void* d_out, int out_size, void* d_ws, size_t ws_size,
                              hipStream_t stream) {
    const float* x      = (const float*)d_in[0];
    const float* es     = (const float*)d_in[1];
    const float* keys   = (const float*)d_in[2];
    const float* values = (const float*)d_in[3];
    float* out          = (float*)d_out;

    // workspace layout (~101 MB)
    char* w = (char*)d_ws;
    int*   cnt      = (int*)w;               w += 256;
    int*   tok_list = (int*)w;               w += (size_t)NEXP * NTOK * sizeof(int);    // 1 MB
    float* gates    = (float*)w;             w += (size_t)NTOK * TOPK * sizeof(float);  // 128 KB
    unsigned short* Kb = (unsigned short*)w; w += (size_t)NEXP * 128 * 128 * 8 * 2;     // 8 MB
    unsigned short* Vb = (unsigned short*)w; w += (size_t)NEXP * 16 * 1024 * 8 * 2;     // 8 MB
    unsigned short* Xb = (unsigned short*)w; w += (size_t)NTOK * DDIM * 2;              // 16.8 MB
    unsigned short* Ob = (unsigned short*)w;                                            // 67 MB

    hipMemsetAsync(cnt, 0, NEXP * sizeof(int), stream);

    prep_gate<<<4096 + NTOK / 16, 256, 0, stream>>>(x, es, keys, values, Kb, Vb, Xb,
                                                    cnt, tok_list, gates);
    ffn_fused<<<128 * NEXP, 256, 0, stream>>>(Xb, Kb, Vb, cnt, tok_list, gates, Ob);
    reduce_out<<<NTOK / 2, 256, 0, stream>>>(Ob, out);
}

// Round 7
// 197.101 us; speedup vs baseline: 1.2623x; 1.0822x over previous
//
#include <hip/hip_runtime.h>
#include <hip/hip_bf16.h>

#define NTOK 8192   // B*S
#define DDIM 1024
#define NEXP 32
#define HDIM 128
#define TOPK 4

typedef __attribute__((ext_vector_type(8))) short bf16x8;
typedef __attribute__((ext_vector_type(4))) float f32x4;

typedef unsigned int uint_g __attribute__((address_space(1)));
typedef unsigned int uint_l __attribute__((address_space(3)));

// async 16B/lane global->LDS; LDS dest = wave-uniform base + lane*16.
__device__ __forceinline__ void async_cp16(const void* g, void* l) {
    __builtin_amdgcn_global_load_lds((const uint_g*)g, (uint_l*)l, 16, 0, 0);
}

__device__ inline unsigned short f2bf(float f) {
    unsigned int u = __builtin_bit_cast(unsigned int, f);
    unsigned int r = (u + 0x7fffu + ((u >> 16) & 1u)) >> 16;   // RNE
    return (unsigned short)r;
}
__device__ inline float bf2f(unsigned short s) {
    unsigned int u = ((unsigned int)s) << 16;
    return __builtin_bit_cast(float, u);
}

// ---------------- Kernel PG: fused gate (blocks 0..511) + prep (blocks 512..4607) ----------
// Gate blocks FIRST in the grid: their 16-chunk latency chains start at t=0 and
// overlap the BW-bound prep blocks that fill in behind them.
// Gate arithmetic is bit-identical to the R6-verified version; the only change is
// register prefetch: chunk t+1's x/es tiles are loaded into regs right after the
// chunk-t LDS writes, hiding HBM latency under barrier+emit+compute.
__global__ __launch_bounds__(256) void prep_gate(
    const float* __restrict__ x, const float* __restrict__ es,
    const float* __restrict__ keys, const float* __restrict__ values,
    unsigned short* __restrict__ Kb, unsigned short* __restrict__ Vb,
    unsigned short* __restrict__ Xb,
    int* __restrict__ cnt, int* __restrict__ tok_list, float* __restrict__ gates)
{
    const int tid = threadIdx.x;

    if (blockIdx.x >= 512) {                 // ---- prep part (no barriers) ----
        int idx = (int)(blockIdx.x - 512) * 256 + tid;
        unsigned short o[8];
        if (idx < NEXP * 128 * 128) {        // keys: (e, k0 [128], n [128])
            int n = idx & 127, k0 = (idx >> 7) & 127, e = idx >> 14;
            const float* s = keys + ((size_t)e * DDIM + k0 * 8) * HDIM + n;
            #pragma unroll
            for (int j = 0; j < 8; ++j) o[j] = f2bf(s[(size_t)j * HDIM]);
            *(uint4*)&Kb[(size_t)idx * 8] = *(uint4*)o;
        } else {                             // values: (e, k0 [16], n [1024])
            idx -= NEXP * 128 * 128;
            int n = idx & 1023, k0 = (idx >> 10) & 15, e = idx >> 14;
            const float* s = values + ((size_t)e * HDIM + k0 * 8) * DDIM + n;
            #pragma unroll
            for (int j = 0; j < 8; ++j) o[j] = f2bf(s[(size_t)j * DDIM]);
            *(uint4*)&Vb[(size_t)idx * 8] = *(uint4*)o;
        }
        return;
    }

    // ---- gate part: 16 tokens, full D=1024, fused x->bf16 emit + top-4 + scatter ----
    const int n0 = (int)blockIdx.x * 16;

    __shared__ float smem[4608];             // staging tiles, reused as Lp each quarter
    __shared__ float Ls[16 * 33];            // final logits
    __shared__ int hist[NEXP];
    __shared__ int bbase[NEXP];
    float* Xt  = smem;                       // [d][tok] stride 36
    float* Est = smem + 64 * 36;             // [d][e]   stride 36
    float* Lp  = smem;                       // [rep 8][tok 16][e 33]

    const int t4  = (tid & 3) * 4;
    const int e4  = ((tid >> 2) & 7) * 4;
    const int rep = tid >> 5;

    const int xr = tid & 15, xc4 = (tid >> 4) * 4;
    const int er = tid & 31, ec8 = (tid >> 5) * 8;

    const int ctok = tid >> 4, cd4 = (tid & 15) * 4;   // x->bf16 emit mapping

    // reduce pairs: (tok, e) and (tok+8, e)
    const int rtok = tid >> 5, re = tid & 31;

    float lsum[2] = {0.f, 0.f};

    if (tid < NEXP) hist[tid] = 0;

    // register preload of chunk dc=0 (x: 1 float4, es: 2 float4 per thread)
    float4 xv  = *(const float4*)&x[(size_t)(n0 + xr) * DDIM + xc4];
    float4 ev0 = *(const float4*)&es[(size_t)er * DDIM + ec8];
    float4 ev1 = *(const float4*)&es[(size_t)er * DDIM + ec8 + 4];

    for (int q = 0; q < 4; ++q) {
        float acc[4][4] = {};

        for (int dci = 0; dci < 4; ++dci) {
            const int dc = q * 256 + dci * 64;
            __syncthreads();                 // prev smem reads (compute / Lp-reduce) done
            {
                Xt[(xc4 + 0) * 36 + xr] = xv.x; Xt[(xc4 + 1) * 36 + xr] = xv.y;
                Xt[(xc4 + 2) * 36 + xr] = xv.z; Xt[(xc4 + 3) * 36 + xr] = xv.w;
                Est[(ec8 + 0) * 36 + er] = ev0.x; Est[(ec8 + 1) * 36 + er] = ev0.y;
                Est[(ec8 + 2) * 36 + er] = ev0.z; Est[(ec8 + 3) * 36 + er] = ev0.w;
                Est[(ec8 + 4) * 36 + er] = ev1.x; Est[(ec8 + 5) * 36 + er] = ev1.y;
                Est[(ec8 + 6) * 36 + er] = ev1.z; Est[(ec8 + 7) * 36 + er] = ev1.w;
            }
            const int nxt = dc + 64;
            if (nxt < DDIM) {                // prefetch next chunk into regs (issued early)
                xv  = *(const float4*)&x[(size_t)(n0 + xr) * DDIM + nxt + xc4];
                ev0 = *(const float4*)&es[(size_t)er * DDIM + nxt + ec8];
                ev1 = *(const float4*)&es[(size_t)er * DDIM + nxt + ec8 + 4];
            }
            __syncthreads();

            // fused: emit this x tile as bf16 (each thread 4 contiguous elems of one row)
            {
                unsigned short o[4];
                #pragma unroll
                for (int j = 0; j < 4; ++j) o[j] = f2bf(Xt[(cd4 + j) * 36 + ctok]);
                *(uint2*)&Xb[(size_t)(n0 + ctok) * DDIM + dc + cd4] = *(uint2*)o;
            }

            #pragma unroll
            for (int s = 0; s < 8; ++s) {
                int d = s * 8 + rep;
                float4 xa4 = *(const float4*)&Xt[d * 36 + t4];
                float4 ea4 = *(const float4*)&Est[d * 36 + e4];
                const float xa[4] = {xa4.x, xa4.y, xa4.z, xa4.w};
                const float ea[4] = {ea4.x, ea4.y, ea4.z, ea4.w};
                #pragma unroll
                for (int i = 0; i < 4; ++i)
                    #pragma unroll
                    for (int j = 0; j < 4; ++j)
                        acc[i][j] = fmaf(xa[i], ea[j], acc[i][j]);
            }
        }

        __syncthreads();                     // Xt/Est reads done; smem -> Lp
        #pragma unroll
        for (int i = 0; i < 4; ++i)
            #pragma unroll
            for (int j = 0; j < 4; ++j)
                Lp[(rep * 16 + t4 + i) * 33 + e4 + j] = acc[i][j];
        __syncthreads();

        #pragma unroll
        for (int h = 0; h < 2; ++h) {        // same reduction order as verified version
            int tok = rtok + h * 8;
            float s = 0.f;
            #pragma unroll
            for (int r = 0; r < 8; ++r) s += Lp[(r * 16 + tok) * 33 + re];
            lsum[h] += s;                    // quarter partials summed in q order
        }
    }

    #pragma unroll
    for (int h = 0; h < 2; ++h) Ls[(rtok + h * 8) * 33 + re] = lsum[h];
    __syncthreads();

    int sel[TOPK]; int lpos[TOPK];
    if (tid < 16) {
        float lg[NEXP];
        #pragma unroll
        for (int e2 = 0; e2 < NEXP; ++e2) lg[e2] = Ls[tid * 33 + e2];
        float sv[TOPK];
        #pragma unroll
        for (int j = 0; j < TOPK; ++j) {
            float bv = -3.0e38f; int bi = 0;
            #pragma unroll
            for (int e2 = 0; e2 < NEXP; ++e2) {
                bool taken = false;
                #pragma unroll
                for (int qq = 0; qq < j; ++qq) taken = taken || (sel[qq] == e2);
                float v = taken ? -3.0e38f : lg[e2];
                if (v > bv) { bv = v; bi = e2; }   // strict >: lowest idx wins ties
            }
            sel[j] = bi; sv[j] = bv;
        }
        #pragma unroll
        for (int j = 0; j < TOPK; ++j) {
            gates[(size_t)(n0 + tid) * TOPK + j] = 1.f / (1.f + expf(-sv[j]));
            lpos[j] = atomicAdd(&hist[sel[j]], 1);
        }
    }
    __syncthreads();
    if (tid < NEXP) bbase[tid] = atomicAdd(&cnt[tid], hist[tid]);
    __syncthreads();
    if (tid < 16) {
        #pragma unroll
        for (int j = 0; j < TOPK; ++j)
            tok_list[(size_t)sel[j] * NTOK + bbase[sel[j]] + lpos[j]] = (n0 + tid) * TOPK + j;
    }
}

// ---------------- Kernel F: fused expert FFN, 32-slot tiles ----------------
// R0's verified two-barrier-per-chunk structure, tile halved 64->32 slots:
// LDS 30.3 KB -> 5 blocks/CU (20 waves/CU) so block-level TLP hides the per-chunk
// staging latency. Grid 8192 (256 tiles x 32 experts), early exit -> refill.
// e = bid&31 keeps all tiles of an expert on XCD e%8 (K_e+V_e L2-resident, 2MB/XCD).
// Every barrier is a full-drain __syncthreads (no counted vmcnt anywhere).
__global__ __launch_bounds__(256) void ffn_fused(
    const unsigned short* __restrict__ Xb,   // [N][1024] bf16
    const unsigned short* __restrict__ Kb,   // [E][128][128][8]
    const unsigned short* __restrict__ Vb,   // [E][16][1024][8]
    const int* __restrict__ cnt, const int* __restrict__ tok_list,
    const float* __restrict__ gates,
    unsigned short* __restrict__ Ob)         // [N*4][1024] bf16
{
    const int bid = blockIdx.x;
    const int e = bid & 31, tile = bid >> 5;
    const int c = cnt[e], base = tile * 32;
    if (base >= c) return;
    const int nt   = min(32, c - base);
    const int tid  = threadIdx.x, wave = tid >> 6, lane = tid & 63;
    const int lm   = lane & 15, quad = lane >> 4;
    const int r2   = (wave >> 1) * 16;       // 16-row half of the 32-slot tile
    const int c2   = (wave & 1) * 64;        // phase A: 64-col half of 128
    const int cw   = (wave & 1) * 32;        // phase B: 32-col half of 64

    __shared__ __align__(16) unsigned short KV[8192];     // 16 KB: K[8][128][8] | V[16][64][8]
    __shared__ __align__(16) unsigned short XO[2304];     // 4.6 KB: A: Xs[8][32][8] | B: OSB[32][72]
    __shared__ __align__(16) unsigned short Hs[32 * 140]; // 8.96 KB (stride 140 -> 16 banks)
    __shared__ int slot[32]; __shared__ int gtok[32]; __shared__ float gs[32];

    if (tid < 32) {
        if (tid < nt) {
            int v = tok_list[(size_t)e * NTOK + base + tid];
            slot[tid] = v; gtok[tid] = v >> 2; gs[tid] = gates[v];
        } else { slot[tid] = -1; gtok[tid] = 0; gs[tid] = 0.f; }
    }
    __syncthreads();

    const unsigned short* Ke = Kb + (size_t)e * 131072;
    const unsigned short* Ve = Vb + (size_t)e * 131072;
    // per-lane X source: lane covers (row = lane&31, k0-offset = lane>>5)
    const unsigned short* xrowb = Xb + (size_t)gtok[lane & 31] * DDIM + (lane >> 5) * 8;

    // ---------------- phase A: H[32][128] = relu(X_tile @ K_e) * g ----------------
    f32x4 acc[4];
    #pragma unroll
    for (int j = 0; j < 4; ++j) acc[j] = (f32x4){0.f, 0.f, 0.f, 0.f};

    auto stageA = [&](int t) {
        int dc = t * 64;
        #pragma unroll
        for (int i = 0; i < 4; ++i) {          // K: 16 x 1KB pieces, 4/wave
            int p = wave * 4 + i;
            async_cp16(Ke + ((size_t)(dc / 8 + (p >> 1)) * 128 + (p & 1) * 64 + lane) * 8,
                       &KV[p * 512]);
        }
        // X: 4 x 1KB pieces (row gather), 1/wave; piece w covers k0 = {2w, 2w+1}
        async_cp16(xrowb + dc + wave * 16, &XO[wave * 512]);
    };

    stageA(0);
    __syncthreads();                           // drain

    for (int t = 0; t < 16; ++t) {
        #pragma unroll
        for (int ks = 0; ks < 2; ++ks) {
            int k0 = ks * 4 + quad;
            bf16x8 a0 = *(const bf16x8*)&XO[(k0 * 32 + r2 + lm) * 8];
            #pragma unroll
            for (int tj = 0; tj < 4; ++tj) {
                bf16x8 bb = *(const bf16x8*)&KV[(k0 * 128 + c2 + tj * 16 + lm) * 8];
                acc[tj] = __builtin_amdgcn_mfma_f32_16x16x32_bf16(a0, bb, acc[tj], 0, 0, 0);
            }
        }
        if (t < 15) {
            __syncthreads();                   // all reads of chunk t done
            stageA(t + 1);
            __syncthreads();                   // drain chunk t+1
        }
    }

    // epilogue A: relu * gate -> Hs (row-major [m][140])
    #pragma unroll
    for (int reg = 0; reg < 4; ++reg) {
        int m = r2 + quad * 4 + reg;
        float g = gs[m];
        #pragma unroll
        for (int tj = 0; tj < 4; ++tj)
            Hs[m * 140 + c2 + tj * 16 + lm] = f2bf(fmaxf(acc[tj][reg], 0.f) * g);
    }
    __syncthreads();                           // Hs complete; KV/XO phase-A reads done

    // ---------------- phase B: Ob = H @ V_e ----------------
    auto stageV = [&](int cc) {
        #pragma unroll
        for (int i = 0; i < 4; ++i) {          // V: 16 x 1KB pieces, 4/wave
            int p = wave * 4 + i;
            async_cp16(Ve + ((size_t)p * 1024 + cc * 64 + lane) * 8, &KV[p * 512]);
        }
    };

    stageV(0);
    __syncthreads();                           // drain

    // hoist H fragments to registers (Hs read-only afterwards)
    bf16x8 hf[4];
    #pragma unroll
    for (int ks = 0; ks < 4; ++ks)
        hf[ks] = *(const bf16x8*)&Hs[(r2 + lm) * 140 + (ks * 4 + quad) * 8];

    const int om = tid >> 3, oq = tid & 7;     // store mapping: 1 uint4/thread
    const int os = slot[om];

    for (int cc = 0; cc < 16; ++cc) {
        f32x4 acc2[2];
        acc2[0] = (f32x4){0.f, 0.f, 0.f, 0.f};
        acc2[1] = (f32x4){0.f, 0.f, 0.f, 0.f};

        #pragma unroll
        for (int ks = 0; ks < 4; ++ks) {
            int k0 = ks * 4 + quad;
            #pragma unroll
            for (int tj = 0; tj < 2; ++tj) {
                bf16x8 bb = *(const bf16x8*)&KV[(k0 * 64 + cw + tj * 16 + lm) * 8];
                acc2[tj] = __builtin_amdgcn_mfma_f32_16x16x32_bf16(hf[ks], bb, acc2[tj], 0, 0, 0);
            }
        }

        // bounce C-tile through LDS (OSB[32][72]) for coalesced 16B stores
        #pragma unroll
        for (int reg = 0; reg < 4; ++reg) {
            int m = r2 + quad * 4 + reg;
            XO[m * 72 + cw + lm]      = f2bf(acc2[0][reg]);
            XO[m * 72 + cw + 16 + lm] = f2bf(acc2[1][reg]);
        }
        __syncthreads();                       // OSB complete; KV reads done

        if (os >= 0) {
            uint4 v0 = *(const uint4*)&XO[om * 72 + oq * 8];
            *(uint4*)(Ob + (size_t)os * DDIM + cc * 64 + oq * 8) = v0;
        }
        if (cc < 15) stageV(cc + 1);
        __syncthreads();                       // drain async; OSB reads done
    }
}

// ---------------- Kernel R: out[n] = sum_j Ob[4n+j]  (bf16 -> fp32) ----------------
__global__ __launch_bounds__(256) void reduce_out(
    const unsigned short* __restrict__ Ob, float* __restrict__ out)
{
    const int tid = threadIdx.x;
    const int n   = blockIdx.x * 2 + (tid >> 7);
    const int cc  = (tid & 127) * 8;

    float s[8] = {};
    #pragma unroll
    for (int j = 0; j < 4; ++j) {
        uint4 v = *(const uint4*)&Ob[((size_t)n * 4 + j) * DDIM + cc];
        const unsigned int w[4] = {v.x, v.y, v.z, v.w};
        #pragma unroll
        for (int q = 0; q < 4; ++q) {
            s[q * 2 + 0] += bf2f((unsigned short)(w[q] & 0xffff));
            s[q * 2 + 1] += bf2f((unsigned short)(w[q] >> 16));
        }
    }
    float4 o0 = {s[0], s[1], s[2], s[3]};
    float4 o1 = {s[4], s[5], s[6], s[7]};
    *(float4*)&out[(size_t)n * DDIM + cc]     = o0;
    *(float4*)&out[(size_t)n * DDIM + cc + 4] = o1;
}

extern "C" void kernel_launch(void* const* d_in, const int* in_sizes, int n_in,
                              void* d_out, int out_size, void* d_ws, size_t ws_size,
                              hipStream_t stream) {
    const float* x      = (const float*)d_in[0];
    const float* es     = (const float*)d_in[1];
    const float* keys   = (const float*)d_in[2];
    const float* values = (const float*)d_in[3];
    float* out          = (float*)d_out;

    // workspace layout (~101 MB)
    char* w = (char*)d_ws;
    int*   cnt      = (int*)w;               w += 256;
    int*   tok_list = (int*)w;               w += (size_t)NEXP * NTOK * sizeof(int);    // 1 MB
    float* gates    = (float*)w;             w += (size_t)NTOK * TOPK * sizeof(float);  // 128 KB
    unsigned short* Kb = (unsigned short*)w; w += (size_t)NEXP * 128 * 128 * 8 * 2;     // 8 MB
    unsigned short* Vb = (unsigned short*)w; w += (size_t)NEXP * 16 * 1024 * 8 * 2;     // 8 MB
    unsigned short* Xb = (unsigned short*)w; w += (size_t)NTOK * DDIM * 2;              // 16.8 MB
    unsigned short* Ob = (unsigned short*)w;                                            // 67 MB

    hipMemsetAsync(cnt, 0, NEXP * sizeof(int), stream);

    prep_gate<<<512 + 4096, 256, 0, stream>>>(x, es, keys, values, Kb, Vb, Xb,
                                              cnt, tok_list, gates);
    ffn_fused<<<256 * NEXP, 256, 0, stream>>>(Xb, Kb, Vb, cnt, tok_list, gates, Ob);
    reduce_out<<<NTOK / 2, 256, 0, stream>>>(Ob, out);
}